// Round 8
// baseline (37160.193 us; speedup 1.0000x reference)
//
#include <hip/hip_runtime.h>
#include <math.h>

// Elman RNN persistent kernel, R8: shrink communication graph (C=16).
// batch=64, T=2048, in=256, hidden=512, out=256, fp32.
// 64 blocks = 4 batch-groups(16 rows) x 16 col-blocks(32 h-cols, 16 y-cols).
// group = blk&3 (=> group members share ~2 XCDs under round-robin; perf only).
// Thread (g=tid&15 k-lane(48 k), cg=(tid>>4)&7 (4 h-cols, 2 y-cols), rp=tid>>7
// (8 rows)): weights in regs: w1r[12][4] float4 (192) + w2r[8][4] float2 (64).
// Per step: poll 64 wave-tags -> sync -> stage h(32KB agent u64)+x to LDS ->
// sync -> fused A/Y-GEMM (96 ds_read_b128) -> 16-lane halving-shuffle reduce
// -> tanh -> h-store(u64 agent) -> per-wave vmcnt(0) -> tag=t+1 -> y store ->
// x(t+1) reg-prefetch. IF$ read traffic 2MB/step (was 8MB in R5-R7).
// Numerics: recurrence fp32 (error amp ~1e4, R1); protocol = R5/R6 proven.

#define BB 64
#define TT 2048
#define II 256
#define HH 512
#define OO 256
#define NBLK 64
#define OUT_OFF ((size_t)BB * TT * OO)
#define LDV 776            // v_s row stride: 768 + 8 pad (16B-aligned rows)

typedef unsigned long long ull;
#define F4C(v,i) ((i)==0?(v).x:((i)==1?(v).y:((i)==2?(v).z:(v).w)))

// recursive-halving reduce over 16 k-lanes (g = lane&15). After HALVE(arr,S,D):
// arr[0..S/2) holds sums of pairs; kept value-index top bit == (g&D)!=0.
#define HALVE(arr, SZ, DIST) { \
    const bool hi_ = (g & (DIST)) != 0; \
    _Pragma("unroll") \
    for (int i_ = 0; i_ < (SZ)/2; ++i_) { \
        float lo_ = arr[i_], hh_ = arr[i_ + (SZ)/2]; \
        float sent_ = hi_ ? lo_ : hh_; \
        float recv_ = __shfl_xor(sent_, (DIST)); \
        arr[i_] = (hi_ ? hh_ : lo_) + recv_; \
    } }

__global__ void rnn_init(int* __restrict__ tags) {
    int i = blockIdx.x * blockDim.x + threadIdx.x;  // 256 = NBLK*4 wave-tags
    tags[i] = 0;
}

__global__ __launch_bounds__(256, 1) void rnn_persist(
    const float* __restrict__ x, const float* __restrict__ W1,
    const float* __restrict__ b1, const float* __restrict__ W2,
    const float* __restrict__ b2, float* __restrict__ out,
    int* __restrict__ tags, float* __restrict__ hbuf)
{
    __shared__ float v_s[16 * LDV];       // [row][768] = [h_t | x_t], ~49.7KB

    const int tid = threadIdx.x;
    const int blk = blockIdx.x;
    const int grp = blk & 3;              // batch group (16 rows)
    const int cb  = blk >> 2;             // col-block 0..15
    const int R0  = grp << 4;
    const int C0  = cb << 5;              // 32 h-cols
    const int O0  = cb << 4;              // 16 y-cols

    const int g  = tid & 15;              // k-lane: k = 64j + 4g + i
    const int cg = (tid >> 4) & 7;        // col group: h-cols cg*4.., y-cols cg*2..
    const int rp = tid >> 7;              // row half: rows rp*8..rp*8+7

    // ---- weights into registers (one-time) ----
    float4 w1r[12][4];
    #pragma unroll
    for (int j = 0; j < 12; ++j)
        #pragma unroll
        for (int i = 0; i < 4; ++i)
            w1r[j][i] = *(const float4*)&W1[(size_t)(j * 64 + (g << 2) + i) * HH
                                            + C0 + (cg << 2)];
    float2 w2r[8][4];
    #pragma unroll
    for (int j = 0; j < 8; ++j)
        #pragma unroll
        for (int i = 0; i < 4; ++i)
            w2r[j][i] = *(const float2*)&W2[(size_t)(j * 64 + (g << 2) + i) * OO
                                            + O0 + (cg << 1)];
    const float2 b1v = *(const float2*)&b1[C0 + (cg << 2) + ((g & 1) << 1)];
    const float  b2v = b2[O0 + (cg << 1) + (g & 1)];

    ull* hb[2] = { (ull*)hbuf, (ull*)(hbuf + (size_t)BB * HH) };

    // output coords after reduce: row rp*8+(g>>1); h-cols C0+cg*4+2*(g&1)+{0,1}
    const int orow = (rp << 3) + (g >> 1);
    const int hcol = C0 + (cg << 2) + ((g & 1) << 1);
    const int ycol = O0 + (cg << 1) + (g & 1);

    // ---- x(0) prefetch to regs ----
    float4 xr[4];
    #pragma unroll
    for (int m = 0; m < 4; ++m) {
        int idx = (m << 8) + tid;         // 0..1023 f4; row=idx>>6, xi=idx&63
        xr[m] = *(const float4*)&x[((size_t)(R0 + (idx >> 6)) * TT + 0) * II
                                   + ((idx & 63) << 2)];
    }

    for (int t = 0; t < TT; ++t) {
        // ---- wait for group's 16 blocks x 4 waves ----
        if (t > 0) {
            if (tid < 64) {
                const int* tp = &tags[((grp + ((tid >> 2) << 2)) << 2) + (tid & 3)];
                while (__hip_atomic_load(tp, __ATOMIC_RELAXED,
                                         __HIP_MEMORY_SCOPE_AGENT) < t) {}
            }
        }
        __syncthreads();                  // SYNC-poll (also: prev y-reads done)

        // ---- stage x(t) from prefetch regs ----
        #pragma unroll
        for (int m = 0; m < 4; ++m) {
            int idx = (m << 8) + tid;
            *(float4*)&v_s[(idx >> 6) * LDV + 512 + ((idx & 63) << 2)] = xr[m];
        }
        // ---- stage h_t: 16 rows x 512 = 4096 u64 agent loads -> LDS ----
        if (t > 0) {
            const ull* hsrc = hb[t & 1];
            #pragma unroll
            for (int half = 0; half < 2; ++half) {
                ull hl[8];
                #pragma unroll
                for (int m = 0; m < 8; ++m) {
                    int idx = (((half << 3) + m) << 8) + tid;  // 0..4095
                    hl[m] = __hip_atomic_load(
                        &hsrc[(size_t)(R0 + (idx >> 8)) * (HH / 2) + (idx & 255)],
                        __ATOMIC_RELAXED, __HIP_MEMORY_SCOPE_AGENT);
                }
                #pragma unroll
                for (int m = 0; m < 8; ++m) {
                    int idx = (((half << 3) + m) << 8) + tid;
                    *(ull*)&v_s[(idx >> 8) * LDV + ((idx & 255) << 1)] = hl[m];
                }
            }
        } else {
            #pragma unroll
            for (int m = 0; m < 8; ++m) {
                int idx = (m << 8) + tid;  // 0..2047 f4 covering 16x512 floats
                *(float4*)&v_s[(idx >> 7) * LDV + ((idx & 127) << 2)] =
                    make_float4(0.f, 0.f, 0.f, 0.f);
            }
        }
        __syncthreads();                  // SYNC-stage

        // ---- fused A-GEMM (K=768) + Y-GEMM (K=512, j<8) ----
        float pa[32];                     // [rr*4 + c]
        float py[16];                     // [rr*2 + o]
        #pragma unroll
        for (int i = 0; i < 32; ++i) pa[i] = 0.f;
        #pragma unroll
        for (int i = 0; i < 16; ++i) py[i] = 0.f;
        #pragma unroll
        for (int rr = 0; rr < 8; ++rr) {
            const float* vrow = v_s + ((rp << 3) + rr) * LDV + (g << 2);
            #pragma unroll
            for (int j = 0; j < 12; ++j) {
                float4 vv = *(const float4*)(vrow + (j << 6));
                #pragma unroll
                for (int i = 0; i < 4; ++i) {
                    const float vi = F4C(vv, i);
                    pa[(rr << 2) + 0] = fmaf(vi, w1r[j][i].x, pa[(rr << 2) + 0]);
                    pa[(rr << 2) + 1] = fmaf(vi, w1r[j][i].y, pa[(rr << 2) + 1]);
                    pa[(rr << 2) + 2] = fmaf(vi, w1r[j][i].z, pa[(rr << 2) + 2]);
                    pa[(rr << 2) + 3] = fmaf(vi, w1r[j][i].w, pa[(rr << 2) + 3]);
                    if (j < 8) {
                        py[(rr << 1) + 0] = fmaf(vi, w2r[j][i].x, py[(rr << 1) + 0]);
                        py[(rr << 1) + 1] = fmaf(vi, w2r[j][i].y, py[(rr << 1) + 1]);
                    }
                }
            }
        }

        // ---- reduce pa over 16 k-lanes; publish h_{t+1} ASAP ----
        HALVE(pa, 32, 8); HALVE(pa, 16, 4); HALVE(pa, 8, 2); HALVE(pa, 4, 1);
        {
            float hv0 = tanhf(pa[0] + b1v.x);
            float hv1 = tanhf(pa[1] + b1v.y);
            ull pk = (ull)__builtin_bit_cast(unsigned, hv0)
                   | ((ull)__builtin_bit_cast(unsigned, hv1) << 32);
            __hip_atomic_store(&hb[(t + 1) & 1][((size_t)(R0 + orow) * HH + hcol) >> 1],
                               pk, __ATOMIC_RELAXED, __HIP_MEMORY_SCOPE_AGENT);
            if (t == TT - 1) {
                out[OUT_OFF + (size_t)(R0 + orow) * HH + hcol]     = hv0;
                out[OUT_OFF + (size_t)(R0 + orow) * HH + hcol + 1] = hv1;
            }
        }
        asm volatile("s_waitcnt vmcnt(0)" ::: "memory");  // wave's h stores at IF$
        if ((tid & 63) == 0)
            __hip_atomic_store(&tags[(blk << 2) + (tid >> 6)], t + 1,
                               __ATOMIC_RELAXED, __HIP_MEMORY_SCOPE_AGENT);

        // ---- y_{t-1} (off critical path) ----
        HALVE(py, 16, 8); HALVE(py, 8, 4); HALVE(py, 4, 2); HALVE(py, 2, 1);
        if (t > 0)
            out[((size_t)(R0 + orow) * TT + (t - 1)) * OO + ycol] = py[0] + b2v;

        // ---- x(t+1) prefetch ----
        if (t + 1 < TT) {
            #pragma unroll
            for (int m = 0; m < 4; ++m) {
                int idx = (m << 8) + tid;
                xr[m] = *(const float4*)&x[((size_t)(R0 + (idx >> 6)) * TT + (t + 1)) * II
                                           + ((idx & 63) << 2)];
            }
        }
    }

    // ---- epilogue: y_{TT-1} from h_TT ----
    if (tid < 64) {
        const int* tp = &tags[((grp + ((tid >> 2) << 2)) << 2) + (tid & 3)];
        while (__hip_atomic_load(tp, __ATOMIC_RELAXED,
                                 __HIP_MEMORY_SCOPE_AGENT) < TT) {}
    }
    __syncthreads();
    {
        const ull* hsrc = hb[TT & 1];     // buf 0
        #pragma unroll
        for (int half = 0; half < 2; ++half) {
            ull hl[8];
            #pragma unroll
            for (int m = 0; m < 8; ++m) {
                int idx = (((half << 3) + m) << 8) + tid;
                hl[m] = __hip_atomic_load(
                    &hsrc[(size_t)(R0 + (idx >> 8)) * (HH / 2) + (idx & 255)],
                    __ATOMIC_RELAXED, __HIP_MEMORY_SCOPE_AGENT);
            }
            #pragma unroll
            for (int m = 0; m < 8; ++m) {
                int idx = (((half << 3) + m) << 8) + tid;
                *(ull*)&v_s[(idx >> 8) * LDV + ((idx & 255) << 1)] = hl[m];
            }
        }
        __syncthreads();
        float py[16];
        #pragma unroll
        for (int i = 0; i < 16; ++i) py[i] = 0.f;
        #pragma unroll
        for (int rr = 0; rr < 8; ++rr) {
            const float* vrow = v_s + ((rp << 3) + rr) * LDV + (g << 2);
            #pragma unroll
            for (int j = 0; j < 8; ++j) {
                float4 vv = *(const float4*)(vrow + (j << 6));
                #pragma unroll
                for (int i = 0; i < 4; ++i) {
                    const float vi = F4C(vv, i);
                    py[(rr << 1) + 0] = fmaf(vi, w2r[j][i].x, py[(rr << 1) + 0]);
                    py[(rr << 1) + 1] = fmaf(vi, w2r[j][i].y, py[(rr << 1) + 1]);
                }
            }
        }
        HALVE(py, 16, 8); HALVE(py, 8, 4); HALVE(py, 4, 2); HALVE(py, 2, 1);
        out[((size_t)(R0 + orow) * TT + (TT - 1)) * OO + ycol] = py[0] + b2v;
    }
}

extern "C" void kernel_launch(void* const* d_in, const int* in_sizes, int n_in,
                              void* d_out, int out_size, void* d_ws, size_t ws_size,
                              hipStream_t stream) {
    const float* x  = (const float*)d_in[0];
    const float* W1 = (const float*)d_in[1];
    const float* b1 = (const float*)d_in[2];
    const float* W2 = (const float*)d_in[3];
    const float* b2 = (const float*)d_in[4];
    float* out = (float*)d_out;

    int*   tags = (int*)d_ws;                         // 64 blocks x 4 waves
    float* hbuf = (float*)((char*)d_ws + 4096);       // 2 x 64x512 f32 = 256KB

    rnn_init<<<dim3(1), dim3(256), 0, stream>>>(tags);
    rnn_persist<<<dim3(NBLK), dim3(256), 0, stream>>>(x, W1, b1, W2, b2, out,
                                                      tags, hbuf);
}

// Round 9
// 20731.398 us; speedup vs baseline: 1.7925x; 1.7925x over previous
//
#include <hip/hip_runtime.h>
#include <math.h>

// Elman RNN persistent kernel, R9 "R5-lean". batch=64,T=2048,in=256,hid=512,out=256 fp32.
// 256 blocks = 4 batch-groups(16 rows) x 64 col-groups(8 h-cols, 4 y-cols), 256 thr.
// GEMM thread (g=tid&31 k-slice, r2=tid>>5 rows {r2,r2+8}): w1r[6][4][8]+w2r[4][4][4]
// in regs; xreg[2][2] per-thread (prefetched 1 step ahead); xw partial computed
// BEFORE the poll (fills wait window). Post-stage GEMM K=512 with y-GEMM fused on
// the same 8 ds_read_b128. Per-wave tag publish (store h -> own vmcnt(0) -> lane0
// tag=t+1); consumers poll 128 tags. 3 __syncthreads/step. LDS: h[16][528] 33KB +
// scratch 24KB. Protocol: relaxed-agent write-through (R3/R5/R6 proven, no fences).
// Numerics: recurrence fp32 (error amp ~1e4, R1). h exchange bit-exact.

#define BB 64
#define TT 2048
#define II 256
#define HH 512
#define OO 256
#define NBLK 256
#define OUT_OFF ((size_t)BB * TT * OO)
#define LDV 528            // h LDS row stride (512+16 pad)

typedef unsigned long long ull;
#define F4C(v,i) ((i)==0?(v).x:((i)==1?(v).y:((i)==2?(v).z:(v).w)))

__global__ void rnn_init(int* __restrict__ tags) {
    int i = blockIdx.x * blockDim.x + threadIdx.x;
    if (i < 2 * NBLK) tags[i] = 0;
}

__global__ __launch_bounds__(256, 1) void rnn_persist(
    const float* __restrict__ x, const float* __restrict__ W1,
    const float* __restrict__ b1, const float* __restrict__ W2,
    const float* __restrict__ b2, float* __restrict__ out,
    int* __restrict__ tags, float* __restrict__ hbuf)
{
    __shared__ float v_s[16 * LDV];       // h_t rows, 33KB
    __shared__ float sc_h[16 * 8 * 32];   // 16KB h partials
    __shared__ float sc_y[16 * 4 * 32];   //  8KB y partials

    const int tid = threadIdx.x;
    const int blk = blockIdx.x;
    const int bi  = blk >> 6;             // batch group (16 rows)
    const int cj  = blk & 63;             // col group
    const int R0  = bi << 4;
    const int C0  = cj << 3;              // 8 h-cols
    const int O0  = cj << 2;              // 4 y-cols

    const int g  = tid & 31;              // k-slice lane
    const int r2 = tid >> 5;              // rows r2, r2+8 (group-local)
    const int oc = tid & 7;               // h reducer col (tid<128)
    const int yi = tid - 128;             // y reducer id (128..191)

    // ---- weights into registers (one-time) ----
    float w1r[6][4][8];
    #pragma unroll
    for (int j = 0; j < 6; ++j)
        #pragma unroll
        for (int i = 0; i < 4; ++i) {
            const float* wp = W1 + (size_t)(j * 128 + (g << 2) + i) * HH + C0;
            float4 a = *(const float4*)wp;
            float4 b = *(const float4*)(wp + 4);
            w1r[j][i][0] = a.x; w1r[j][i][1] = a.y; w1r[j][i][2] = a.z; w1r[j][i][3] = a.w;
            w1r[j][i][4] = b.x; w1r[j][i][5] = b.y; w1r[j][i][6] = b.z; w1r[j][i][7] = b.w;
        }
    float w2r[4][4][4];
    #pragma unroll
    for (int j = 0; j < 4; ++j)
        #pragma unroll
        for (int i = 0; i < 4; ++i) {
            float4 a = *(const float4*)(W2 + (size_t)(j * 128 + (g << 2) + i) * OO + O0);
            w2r[j][i][0] = a.x; w2r[j][i][1] = a.y; w2r[j][i][2] = a.z; w2r[j][i][3] = a.w;
        }
    const float b1v = (tid < 128) ? b1[C0 + oc] : 0.f;
    const float b2v = (tid >= 128 && tid < 192) ? b2[O0 + (yi & 3)] : 0.f;

    float* hb[2] = { hbuf, hbuf + (size_t)BB * HH };

    // ---- zero v_s h region once (16 rows x 512) ----
    #pragma unroll
    for (int m = 0; m < 8; ++m) {
        int idx = (m << 8) + tid;         // 0..2047 float4
        *(float4*)&v_s[(idx >> 7) * LDV + ((idx & 127) << 2)] =
            make_float4(0.f, 0.f, 0.f, 0.f);
    }
    // ---- xreg for t=0 ----
    float4 xreg[2][2];
    #pragma unroll
    for (int rr = 0; rr < 2; ++rr)
        #pragma unroll
        for (int jx = 0; jx < 2; ++jx)
            xreg[rr][jx] = *(const float4*)&x[((size_t)(R0 + r2 + (rr << 3)) * TT + 0) * II
                                              + (jx << 7) + (g << 2)];
    __syncthreads();

    for (int t = 0; t < TT; ++t) {
        // ---- phase 1: xw partial from regs (fills poll window) ----
        float pa[2][8];
        float py[2][4];
        #pragma unroll
        for (int rr = 0; rr < 2; ++rr) {
            #pragma unroll
            for (int c = 0; c < 8; ++c) pa[rr][c] = 0.f;
            #pragma unroll
            for (int o = 0; o < 4; ++o) py[rr][o] = 0.f;
        }
        #pragma unroll
        for (int rr = 0; rr < 2; ++rr)
            #pragma unroll
            for (int jx = 0; jx < 2; ++jx) {
                float4 vv = xreg[rr][jx];
                #pragma unroll
                for (int i = 0; i < 4; ++i) {
                    const float vi = F4C(vv, i);
                    #pragma unroll
                    for (int c = 0; c < 8; ++c)
                        pa[rr][c] = fmaf(vi, w1r[4 + jx][i][c], pa[rr][c]);
                }
            }
        // ---- phase 2: poll group's 64 blocks x 2 wave-tags ----
        if (t > 0 && tid < 128) {
            const int* tp = &tags[((bi << 6) + (tid >> 1)) * 2 + (tid & 1)];
            while (__hip_atomic_load(tp, __ATOMIC_RELAXED,
                                     __HIP_MEMORY_SCOPE_AGENT) < t) {}
        }
        __syncthreads();                  // S1
        // ---- phase 3: stage h_t (16 rows x 512 f = 4096 u64, coalesced) ----
        if (t > 0) {
            const ull* hsrc = (const ull*)hb[t & 1];
            #pragma unroll
            for (int half = 0; half < 2; ++half) {
                ull hl[8];
                #pragma unroll
                for (int m = 0; m < 8; ++m) {
                    int idx = (((half << 3) + m) << 8) + tid;   // 0..4095
                    hl[m] = __hip_atomic_load(
                        &hsrc[(size_t)(R0 + (idx >> 8)) * (HH / 2) + (idx & 255)],
                        __ATOMIC_RELAXED, __HIP_MEMORY_SCOPE_AGENT);
                }
                #pragma unroll
                for (int m = 0; m < 8; ++m) {
                    int idx = (((half << 3) + m) << 8) + tid;
                    *(ull*)&v_s[(idx >> 8) * LDV + ((idx & 255) << 1)] = hl[m];
                }
            }
        }
        __syncthreads();                  // S2
        // ---- phase 4: prefetch xreg for t+1 (latency hides under GEMM) ----
        if (t + 1 < TT) {
            #pragma unroll
            for (int rr = 0; rr < 2; ++rr)
                #pragma unroll
                for (int jx = 0; jx < 2; ++jx)
                    xreg[rr][jx] = *(const float4*)&x[((size_t)(R0 + r2 + (rr << 3)) * TT
                                                      + (t + 1)) * II + (jx << 7) + (g << 2)];
        }
        // ---- phase 5: fused h-GEMM (K=512) + y-GEMM on shared ds_reads ----
        #pragma unroll
        for (int rr = 0; rr < 2; ++rr) {
            const float* vrow = v_s + (r2 + (rr << 3)) * LDV + (g << 2);
            #pragma unroll
            for (int j = 0; j < 4; ++j) {
                float4 vv = *(const float4*)(vrow + (j << 7));
                #pragma unroll
                for (int i = 0; i < 4; ++i) {
                    const float vi = F4C(vv, i);
                    #pragma unroll
                    for (int c = 0; c < 8; ++c)
                        pa[rr][c] = fmaf(vi, w1r[j][i][c], pa[rr][c]);
                    #pragma unroll
                    for (int o = 0; o < 4; ++o)
                        py[rr][o] = fmaf(vi, w2r[j][i][o], py[rr][o]);
                }
            }
        }
        // ---- phase 6: partials to swizzled scratch ----
        #pragma unroll
        for (int rr = 0; rr < 2; ++rr) {
            const int row16 = r2 + (rr << 3);
            #pragma unroll
            for (int c = 0; c < 8; ++c)
                sc_h[(((row16 << 3) + c) << 5) + (g ^ (c << 2))] = pa[rr][c];
            #pragma unroll
            for (int o = 0; o < 4; ++o)
                sc_y[(((row16 << 2) + o) << 5) + (g ^ (o << 2))] = py[rr][o];
        }
        __syncthreads();                  // S3
        // ---- phase 7: split finish ----
        if (tid < 128) {
            float s = 0.f;
            #pragma unroll
            for (int j = 0; j < 8; ++j) {
                float4 q = *(const float4*)&sc_h[(tid << 5) + ((j << 2) ^ (oc << 2))];
                s += (q.x + q.y) + (q.z + q.w);
            }
            float hv = tanhf(s + b1v);
            __hip_atomic_store(&hb[(t + 1) & 1][(size_t)(R0 + (tid >> 3)) * HH + C0 + oc],
                               hv, __ATOMIC_RELAXED, __HIP_MEMORY_SCOPE_AGENT);
            if (t == TT - 1)
                out[OUT_OFF + (size_t)(R0 + (tid >> 3)) * HH + C0 + oc] = hv;
            asm volatile("s_waitcnt vmcnt(0)" ::: "memory");   // this wave's stores at IF$
            if ((tid & 63) == 0)
                __hip_atomic_store(&tags[(blk << 1) + (tid >> 6)], t + 1,
                                   __ATOMIC_RELAXED, __HIP_MEMORY_SCOPE_AGENT);
        } else if (tid < 192 && t > 0) {
            float s = 0.f;
            #pragma unroll
            for (int j = 0; j < 8; ++j) {
                float4 q = *(const float4*)&sc_y[(yi << 5) + ((j << 2) ^ ((yi & 3) << 2))];
                s += (q.x + q.y) + (q.z + q.w);
            }
            out[((size_t)(R0 + (yi >> 2)) * TT + (t - 1)) * OO + O0 + (yi & 3)] = s + b2v;
        }
    }

    // ---- epilogue: y_{TT-1} from h_TT ----
    if (tid < 128) {
        const int* tp = &tags[((bi << 6) + (tid >> 1)) * 2 + (tid & 1)];
        while (__hip_atomic_load(tp, __ATOMIC_RELAXED,
                                 __HIP_MEMORY_SCOPE_AGENT) < TT) {}
    }
    __syncthreads();
    {
        const ull* hsrc = (const ull*)hb[TT & 1];   // buf 0
        #pragma unroll
        for (int half = 0; half < 2; ++half) {
            ull hl[8];
            #pragma unroll
            for (int m = 0; m < 8; ++m) {
                int idx = (((half << 3) + m) << 8) + tid;
                hl[m] = __hip_atomic_load(
                    &hsrc[(size_t)(R0 + (idx >> 8)) * (HH / 2) + (idx & 255)],
                    __ATOMIC_RELAXED, __HIP_MEMORY_SCOPE_AGENT);
            }
            #pragma unroll
            for (int m = 0; m < 8; ++m) {
                int idx = (((half << 3) + m) << 8) + tid;
                *(ull*)&v_s[(idx >> 8) * LDV + ((idx & 255) << 1)] = hl[m];
            }
        }
        __syncthreads();
        float py[2][4];
        #pragma unroll
        for (int rr = 0; rr < 2; ++rr) {
            #pragma unroll
            for (int o = 0; o < 4; ++o) py[rr][o] = 0.f;
            const float* vrow = v_s + (r2 + (rr << 3)) * LDV + (g << 2);
            #pragma unroll
            for (int j = 0; j < 4; ++j) {
                float4 vv = *(const float4*)(vrow + (j << 7));
                #pragma unroll
                for (int i = 0; i < 4; ++i) {
                    const float vi = F4C(vv, i);
                    #pragma unroll
                    for (int o = 0; o < 4; ++o)
                        py[rr][o] = fmaf(vi, w2r[j][i][o], py[rr][o]);
                }
            }
            const int row16 = r2 + (rr << 3);
            #pragma unroll
            for (int o = 0; o < 4; ++o)
                sc_y[(((row16 << 2) + o) << 5) + (g ^ (o << 2))] = py[rr][o];
        }
        __syncthreads();
        if (tid >= 128 && tid < 192) {
            float s = 0.f;
            #pragma unroll
            for (int j = 0; j < 8; ++j) {
                float4 q = *(const float4*)&sc_y[(yi << 5) + ((j << 2) ^ ((yi & 3) << 2))];
                s += (q.x + q.y) + (q.z + q.w);
            }
            out[((size_t)(R0 + (yi >> 2)) * TT + (TT - 1)) * OO + O0 + (yi & 3)] = s + b2v;
        }
    }
}

extern "C" void kernel_launch(void* const* d_in, const int* in_sizes, int n_in,
                              void* d_out, int out_size, void* d_ws, size_t ws_size,
                              hipStream_t stream) {
    const float* x  = (const float*)d_in[0];
    const float* W1 = (const float*)d_in[1];
    const float* b1 = (const float*)d_in[2];
    const float* W2 = (const float*)d_in[3];
    const float* b2 = (const float*)d_in[4];
    float* out = (float*)d_out;

    int*   tags = (int*)d_ws;                      // 512 wave-tags
    float* hbuf = (float*)((char*)d_ws + 4096);    // 2 x 64x512 f32 = 256KB

    rnn_init<<<dim3(2), dim3(256), 0, stream>>>(tags);
    rnn_persist<<<dim3(NBLK), dim3(256), 0, stream>>>(x, W1, b1, W2, b2, out,
                                                      tags, hbuf);
}

// Round 11
// 11666.289 us; speedup vs baseline: 3.1853x; 1.7770x over previous
//
#include <hip/hip_runtime.h>
#include <math.h>

// Elman RNN persistent kernel, R11 (= R10 + ext_vector_type NT fix).
// batch=64,T=2048,in=256,hid=512,out=256 fp32.
// 256 blocks = 4 groups(16 rows) x 64 col-groups(8 h-cols, 4 y-cols), 256 thr.
// 64-lane k-slices (g=tid&63, k=4g+256jj): w1r[3][4][8]+w2r[2][4][4] = 128
// weight floats/thread -> NO VGPR spill (R9 lesson: 256-cap = scratch in loop).
// Per-thread targeted poll->stage: thread stages u64-col tid of rows 0..15, all
// from producer block tid>>2 -> polls that one per-step flag (R5 rotating array).
// y-GEMM fused on same LDS reads; xw from regs pre-poll; x prefetch AFTER
// publish (R9 lesson: never leave HBM loads outstanding across publish vmcnt).
// NT loads/stores for x/y (zero reuse) protect h/flag lines in IF$ (FETCH
// evidence: 1.6GB/dispatch = h lines thrashed to HBM by x/y streams).
// NT via clang ext_vector_type (HIP float4 struct rejected by the builtin).
// Protocol: relaxed-agent write-through everywhere (R3/R5 proven, no fences).
// Numerics: recurrence fp32 (error amp ~1e4, R1); h exchange bit-exact.

#define BB 64
#define TT 2048
#define II 256
#define HH 512
#define OO 256
#define NBLK 256
#define OUT_OFF ((size_t)BB * TT * OO)
#define FLAGS_INTS ((TT + 1) * NBLK)

typedef unsigned long long ull;
typedef float fx4 __attribute__((ext_vector_type(4)));

__global__ void rnn_init(int* __restrict__ flags) {
    int i = blockIdx.x * blockDim.x + threadIdx.x;
    if (i < FLAGS_INTS) flags[i] = 0;
}

__global__ __launch_bounds__(256, 1) void rnn_persist(
    const float* __restrict__ x, const float* __restrict__ W1,
    const float* __restrict__ b1, const float* __restrict__ W2,
    const float* __restrict__ b2, float* __restrict__ out,
    int* __restrict__ flags, float* __restrict__ hbuf)
{
    __shared__ float v_s[16 * HH];        // 32KB h rows (no pad: all reads coalesced)
    __shared__ float sc_h[128 * 64];      // 32KB h partials (unit=row*8+c)
    __shared__ float sc_y[64 * 64];       // 16KB y partials (unit=row*4+o)

    const int tid = threadIdx.x;
    const int blk = blockIdx.x;
    const int bi  = blk >> 6;             // batch group (16 rows)
    const int cj  = blk & 63;             // col group
    const int R0  = bi << 4;
    const int C0  = cj << 3;              // 8 h-cols
    const int O0  = cj << 2;              // 4 y-cols

    const int g  = tid & 63;              // k-lane: k = 4g+i + 256jj
    const int rq = tid >> 6;              // rows rq, rq+4, rq+8, rq+12

    // ---- weights into registers: 96 + 32 floats ----
    float w1r[3][4][8];                   // jj=0,1: h-k; jj=2: x-k
    #pragma unroll
    for (int jj = 0; jj < 2; ++jj)
        #pragma unroll
        for (int i = 0; i < 4; ++i) {
            const float* wp = W1 + (size_t)((jj << 8) + (g << 2) + i) * HH + C0;
            float4 a = *(const float4*)wp;
            float4 b = *(const float4*)(wp + 4);
            w1r[jj][i][0]=a.x; w1r[jj][i][1]=a.y; w1r[jj][i][2]=a.z; w1r[jj][i][3]=a.w;
            w1r[jj][i][4]=b.x; w1r[jj][i][5]=b.y; w1r[jj][i][6]=b.z; w1r[jj][i][7]=b.w;
        }
    #pragma unroll
    for (int i = 0; i < 4; ++i) {
        const float* wp = W1 + (size_t)(HH + (g << 2) + i) * HH + C0;
        float4 a = *(const float4*)wp;
        float4 b = *(const float4*)(wp + 4);
        w1r[2][i][0]=a.x; w1r[2][i][1]=a.y; w1r[2][i][2]=a.z; w1r[2][i][3]=a.w;
        w1r[2][i][4]=b.x; w1r[2][i][5]=b.y; w1r[2][i][6]=b.z; w1r[2][i][7]=b.w;
    }
    float w2r[2][4][4];
    #pragma unroll
    for (int jj = 0; jj < 2; ++jj)
        #pragma unroll
        for (int i = 0; i < 4; ++i) {
            float4 a = *(const float4*)(W2 + (size_t)((jj << 8) + (g << 2) + i) * OO + O0);
            w2r[jj][i][0]=a.x; w2r[jj][i][1]=a.y; w2r[jj][i][2]=a.z; w2r[jj][i][3]=a.w;
        }
    const float b1v = (tid < 128) ? b1[C0 + (tid & 7)] : 0.f;
    const float b2v = (tid >= 128 && tid < 192) ? b2[O0 + ((tid - 128) & 3)] : 0.f;

    float* hb[2] = { hbuf, hbuf + (size_t)BB * HH };

    // ---- zero v_s (h_0 = 0): 2048 float4 ----
    #pragma unroll
    for (int m = 0; m < 8; ++m)
        *(float4*)&v_s[((m << 8) + tid) << 2] = make_float4(0.f, 0.f, 0.f, 0.f);

    // ---- x(0) NT prefetch: 4 rows x fx4 (k = 4g..4g+3) ----
    fx4 xreg[4];
    #pragma unroll
    for (int r = 0; r < 4; ++r)
        xreg[r] = __builtin_nontemporal_load(
            (const fx4*)&x[((size_t)(R0 + rq + (r << 2)) * TT + 0) * II + (g << 2)]);
    __syncthreads();

    for (int t = 0; t < TT; ++t) {
        // ---- phase 0: xw partials from regs (fills poll window) ----
        float pa[4][8];
        float py[4][4];
        #pragma unroll
        for (int r = 0; r < 4; ++r) {
            #pragma unroll
            for (int c = 0; c < 8; ++c) pa[r][c] = 0.f;
            #pragma unroll
            for (int o = 0; o < 4; ++o) py[r][o] = 0.f;
        }
        #pragma unroll
        for (int r = 0; r < 4; ++r) {
            fx4 vv = xreg[r];
            #pragma unroll
            for (int i = 0; i < 4; ++i) {
                const float vi = vv[i];
                #pragma unroll
                for (int c = 0; c < 8; ++c)
                    pa[r][c] = fmaf(vi, w1r[2][i][c], pa[r][c]);
            }
        }
        // ---- phase 1+2: targeted poll (producer = block tid>>2) + stage ----
        if (t > 0) {
            const int* fp = flags + (size_t)t * NBLK + (bi << 6) + (tid >> 2);
            while (__hip_atomic_load((int*)fp, __ATOMIC_RELAXED,
                                     __HIP_MEMORY_SCOPE_AGENT) == 0) {}
            const ull* hsrc = (const ull*)hb[t & 1];
            ull* vd = (ull*)v_s;
            #pragma unroll
            for (int half = 0; half < 2; ++half) {
                ull hl[8];
                #pragma unroll
                for (int m = 0; m < 8; ++m) {
                    int row = (half << 3) + m;
                    hl[m] = __hip_atomic_load(
                        (ull*)&hsrc[(size_t)(R0 + row) * (HH / 2) + tid],
                        __ATOMIC_RELAXED, __HIP_MEMORY_SCOPE_AGENT);
                }
                #pragma unroll
                for (int m = 0; m < 8; ++m) {
                    int row = (half << 3) + m;
                    vd[row * (HH / 2) + tid] = hl[m];
                }
            }
        }
        __syncthreads();                  // S1: stage complete

        // ---- phase 3: fused h-GEMM (K=512) + y-GEMM on shared ds_reads ----
        #pragma unroll
        for (int r = 0; r < 4; ++r) {
            const float* vrow = v_s + (rq + (r << 2)) * HH;
            #pragma unroll
            for (int jj = 0; jj < 2; ++jj) {
                float4 vv = *(const float4*)(vrow + (jj << 8) + (g << 2));
                float vva[4] = { vv.x, vv.y, vv.z, vv.w };
                #pragma unroll
                for (int i = 0; i < 4; ++i) {
                    const float vi = vva[i];
                    #pragma unroll
                    for (int c = 0; c < 8; ++c)
                        pa[r][c] = fmaf(vi, w1r[jj][i][c], pa[r][c]);
                    #pragma unroll
                    for (int o = 0; o < 4; ++o)
                        py[r][o] = fmaf(vi, w2r[jj][i][o], py[r][o]);
                }
            }
        }
        // ---- phase 4: partials to swizzled scratch ----
        #pragma unroll
        for (int r = 0; r < 4; ++r) {
            const int row = rq + (r << 2);
            #pragma unroll
            for (int c = 0; c < 8; ++c) {
                const int u = (row << 3) + c;
                sc_h[(u << 6) + (g ^ ((u & 15) << 2))] = pa[r][c];
            }
            #pragma unroll
            for (int o = 0; o < 4; ++o) {
                const int u = (row << 2) + o;
                sc_y[(u << 6) + (g ^ ((u & 15) << 2))] = py[r][o];
            }
        }
        __syncthreads();                  // S2: partials visible

        // ---- phase 5: split finish ----
        if (tid < 128) {
            float s = 0.f;
            #pragma unroll
            for (int j = 0; j < 16; ++j) {
                float4 q = *(const float4*)&sc_h[(tid << 6) + ((j << 2) ^ ((tid & 15) << 2))];
                s += (q.x + q.y) + (q.z + q.w);
            }
            float hv = tanhf(s + b1v);
            __hip_atomic_store(&hb[(t + 1) & 1][(size_t)(R0 + (tid >> 3)) * HH + C0 + (tid & 7)],
                               hv, __ATOMIC_RELAXED, __HIP_MEMORY_SCOPE_AGENT);
            if (t == TT - 1)
                out[OUT_OFF + (size_t)(R0 + (tid >> 3)) * HH + C0 + (tid & 7)] = hv;
        } else if (tid < 192 && t > 0) {
            const int u = tid - 128;
            float s = 0.f;
            #pragma unroll
            for (int j = 0; j < 16; ++j) {
                float4 q = *(const float4*)&sc_y[(u << 6) + ((j << 2) ^ ((u & 15) << 2))];
                s += (q.x + q.y) + (q.z + q.w);
            }
            __builtin_nontemporal_store(s + b2v,
                &out[((size_t)(R0 + (u >> 2)) * TT + (t - 1)) * OO + O0 + (u & 3)]);
        }
        // ---- phase 6: publish (R5-proven: block drain -> single flag) ----
        asm volatile("s_waitcnt vmcnt(0)" ::: "memory");
        __syncthreads();                  // S3
        if (tid == 0)
            __hip_atomic_store(&flags[(size_t)(t + 1) * NBLK + blk], 1,
                               __ATOMIC_RELAXED, __HIP_MEMORY_SCOPE_AGENT);
        // ---- phase 7: x(t+1) NT prefetch (AFTER publish) ----
        if (t + 1 < TT) {
            #pragma unroll
            for (int r = 0; r < 4; ++r)
                xreg[r] = __builtin_nontemporal_load(
                    (const fx4*)&x[((size_t)(R0 + rq + (r << 2)) * TT + (t + 1)) * II + (g << 2)]);
        }
    }

    // ---- epilogue: y_{TT-1} from h_TT ----
    {
        const int* fp = flags + (size_t)TT * NBLK + (bi << 6) + (tid >> 2);
        while (__hip_atomic_load((int*)fp, __ATOMIC_RELAXED,
                                 __HIP_MEMORY_SCOPE_AGENT) == 0) {}
        const ull* hsrc = (const ull*)hb[TT & 1];   // buf 0
        ull* vd = (ull*)v_s;
        #pragma unroll
        for (int half = 0; half < 2; ++half) {
            ull hl[8];
            #pragma unroll
            for (int m = 0; m < 8; ++m) {
                int row = (half << 3) + m;
                hl[m] = __hip_atomic_load(
                    (ull*)&hsrc[(size_t)(R0 + row) * (HH / 2) + tid],
                    __ATOMIC_RELAXED, __HIP_MEMORY_SCOPE_AGENT);
            }
            #pragma unroll
            for (int m = 0; m < 8; ++m) {
                int row = (half << 3) + m;
                vd[row * (HH / 2) + tid] = hl[m];
            }
        }
        __syncthreads();
        float py[4][4];
        #pragma unroll
        for (int r = 0; r < 4; ++r) {
            #pragma unroll
            for (int o = 0; o < 4; ++o) py[r][o] = 0.f;
            const float* vrow = v_s + (rq + (r << 2)) * HH;
            #pragma unroll
            for (int jj = 0; jj < 2; ++jj) {
                float4 vv = *(const float4*)(vrow + (jj << 8) + (g << 2));
                float vva[4] = { vv.x, vv.y, vv.z, vv.w };
                #pragma unroll
                for (int i = 0; i < 4; ++i) {
                    const float vi = vva[i];
                    #pragma unroll
                    for (int o = 0; o < 4; ++o)
                        py[r][o] = fmaf(vi, w2r[jj][i][o], py[r][o]);
                }
            }
            const int row = rq + (r << 2);
            #pragma unroll
            for (int o = 0; o < 4; ++o) {
                const int u = (row << 2) + o;
                sc_y[(u << 6) + (g ^ ((u & 15) << 2))] = py[r][o];
            }
        }
        __syncthreads();
        if (tid >= 128 && tid < 192) {
            const int u = tid - 128;
            float s = 0.f;
            #pragma unroll
            for (int j = 0; j < 16; ++j) {
                float4 q = *(const float4*)&sc_y[(u << 6) + ((j << 2) ^ ((u & 15) << 2))];
                s += (q.x + q.y) + (q.z + q.w);
            }
            out[((size_t)(R0 + (u >> 2)) * TT + (TT - 1)) * OO + O0 + (u & 3)] = s + b2v;
        }
    }
}

extern "C" void kernel_launch(void* const* d_in, const int* in_sizes, int n_in,
                              void* d_out, int out_size, void* d_ws, size_t ws_size,
                              hipStream_t stream) {
    const float* x  = (const float*)d_in[0];
    const float* W1 = (const float*)d_in[1];
    const float* b1 = (const float*)d_in[2];
    const float* W2 = (const float*)d_in[3];
    const float* b2 = (const float*)d_in[4];
    float* out = (float*)d_out;

    float* hbuf  = (float*)d_ws;                        // 256KB ping-pong
    int*   flags = (int*)((char*)d_ws + 512 * 1024);    // (TT+1)*256 ints

    rnn_init<<<dim3((FLAGS_INTS + 255) / 256), dim3(256), 0, stream>>>(flags);
    rnn_persist<<<dim3(NBLK), dim3(256), 0, stream>>>(x, W1, b1, W2, b2, out,
                                                      flags, hbuf);
}